// Round 15
// baseline (178.782 us; speedup 1.0000x reference)
//
#include <hip/hip_runtime.h>
#include <hip/hip_bf16.h>
#include <stdint.h>

typedef __attribute__((ext_vector_type(8))) short short8;
typedef __attribute__((ext_vector_type(4))) float f32x4;
typedef __attribute__((ext_vector_type(16))) float f32x16;

#define AS1 __attribute__((address_space(1)))
#define AS3 __attribute__((address_space(3)))

constexpr int Bc = 4, Sc = 2048, Dc = 1024, Hc = 16;

__device__ __forceinline__ unsigned short f2b(float x) {
  __hip_bfloat16 h = __float2bfloat16(x);
  return *reinterpret_cast<unsigned short*>(&h);
}

__device__ __forceinline__ uint32_t cvtpk(float lo, float hi) {
  uint32_t r;
  asm("v_cvt_pk_bf16_f32 %0, %1, %2" : "=v"(r) : "v"(lo), "v"(hi));
  return r;
}

// async global->LDS, 16B per lane; lds ptr must be wave-uniform (HW adds lane*16)
__device__ __forceinline__ void glds16(const void* g, void* l) {
  __builtin_amdgcn_global_load_lds((const AS1 uint32_t*)g, (AS3 uint32_t*)l, 16, 0, 0);
}

// ------------------------------------------------- weight cast (grid 1024,4)
__global__ void cast_w4(const float* __restrict__ wq, const float* __restrict__ wk,
                        const float* __restrict__ wv, const float* __restrict__ wo,
                        unsigned short* __restrict__ oq, unsigned short* __restrict__ ok,
                        unsigned short* __restrict__ ov, unsigned short* __restrict__ oo) {
  int which = blockIdx.y;
  const float* in = which == 0 ? wq : which == 1 ? wk : which == 2 ? wv : wo;
  unsigned short* out = which == 0 ? oq : which == 1 ? ok : which == 2 ? ov : oo;
  int i = blockIdx.x * blockDim.x + threadIdx.x;
  float4 a = ((const float4*)in)[i];
  ushort4 o;
  o.x = f2b(a.x); o.y = f2b(a.y); o.z = f2b(a.z); o.w = f2b(a.w);
  ((ushort4*)out)[i] = o;
}

// ------------------------------- 128x128 GEMM core, BK=32, f32-A fused cast
// r15: r4's proven 2-phase structure (single buffers, stage -> __syncthreads
// -> ds_read+MFMA -> __syncthreads) with A read DIRECTLY from f32 x:
// stage 128x32 f32 A-tile (16KB) via glds16, convert to bf16 at fragment
// read with v_cvt_pk_bf16_f32 (inside the hidden compute phase). Deletes the
// x-cast kernel's 16MB write + 16MB re-read. A rows are 128B -> fragment
// reads use both-sides XOR swizzle (chunk ^= row&7 on source, same XOR on
// the two 16B half-fragment reads -> 2-way = free). B path byte-identical
// to r4 (bf16 weights, conflicts accepted per regime gate).
template<int MODE>
__device__ __forceinline__ void gemm128_xf32(
    const float* __restrict__ A, const unsigned short* __restrict__ W,
    const float* __restrict__ bias, void* __restrict__ outp,
    int m0, int n0, float* lA, unsigned short* lB)
{
  const int tid = threadIdx.x;
  const int w = tid >> 6, lane = tid & 63;
  const int g = lane >> 4, c = lane & 15;
  const int wr = w >> 1, wc = w & 1;

  f32x4 acc[4][4];
#pragma unroll
  for (int i = 0; i < 4; ++i)
#pragma unroll
    for (int j = 0; j < 4; ++j) acc[i][j] = f32x4{0.f, 0.f, 0.f, 0.f};

  // ---- A staging (f32): 8-row stripes, swizzled source chunk (4 floats)
  const int arow8 = lane >> 3;              // 0..7 row within stripe
  const int ach = (lane & 7) ^ arow8;       // pre-swizzled 16B chunk index
  const float* ap[4];
#pragma unroll
  for (int i = 0; i < 2; ++i)
#pragma unroll
    for (int j = 0; j < 2; ++j)
      ap[i * 2 + j] = A + (size_t)(m0 + i * 64 + w * 16 + j * 8 + arow8) * 1024 + ach * 4;

  // ---- B staging (bf16): r4 verbatim
  const int srow = lane >> 2;
  const int schunk = (lane & 3) * 8;
  const unsigned short* b0 = W + (size_t)(n0 + w * 16 + srow) * 1024 + schunk;
  const unsigned short* b1 = b0 + (size_t)64 * 1024;

#define STAGEX                                                        \
  do {                                                                \
    _Pragma("unroll")                                                 \
    for (int i = 0; i < 2; ++i)                                       \
      _Pragma("unroll")                                               \
      for (int j = 0; j < 2; ++j) {                                   \
        glds16(ap[i * 2 + j],                                         \
               (char*)lA + (i * 64 + w * 16 + j * 8) * 128);          \
        ap[i * 2 + j] += 32;                                          \
      }                                                               \
    glds16(b0, (char*)lB + w * 1024);                                 \
    glds16(b1, (char*)lB + 4096 + w * 1024);                          \
    b0 += 32; b1 += 32;                                               \
  } while (0)

  // A fragment read slots (swizzled): fragment g = chunks 2g, 2g+1 of row c
  const int as1 = ((2 * g) ^ (c & 7)) * 16;
  const int as2 = ((2 * g + 1) ^ (c & 7)) * 16;

  STAGEX;
  for (int t = 0; t < 32; ++t) {
    __syncthreads();

    short8 aF[4], bF[4];
#pragma unroll
    for (int mt = 0; mt < 4; ++mt) {
      int row = wr * 64 + mt * 16 + c;
      f32x4 a0 = *(const f32x4*)((const char*)lA + row * 128 + as1);
      f32x4 a1 = *(const f32x4*)((const char*)lA + row * 128 + as2);
      uint32_t u[4] = { cvtpk(a0[0], a0[1]), cvtpk(a0[2], a0[3]),
                        cvtpk(a1[0], a1[1]), cvtpk(a1[2], a1[3]) };
      aF[mt] = *(const short8*)u;
    }
#pragma unroll
    for (int nt = 0; nt < 4; ++nt) {
      int row = wc * 64 + nt * 16 + c;
      bF[nt] = *(const short8*)&lB[row * 32 + g * 8];
    }
#pragma unroll
    for (int mt = 0; mt < 4; ++mt)
#pragma unroll
      for (int nt = 0; nt < 4; ++nt)
        acc[mt][nt] = __builtin_amdgcn_mfma_f32_16x16x32_bf16(aF[mt], bF[nt],
                                                              acc[mt][nt], 0, 0, 0);
    __syncthreads();
    if (t + 1 < 32) STAGEX;
  }
#undef STAGEX

  // epilogue: C row = 4g+reg, col = c (per 16x16 tile)
#pragma unroll
  for (int mt = 0; mt < 4; ++mt) {
    int mg = m0 + wr * 64 + mt * 16 + 4 * g;
#pragma unroll
    for (int nt = 0; nt < 4; ++nt) {
      int ng = n0 + wc * 64 + nt * 16 + c;
      float bb_ = bias[ng];
      if constexpr (MODE == 0) {
        unsigned short* o = (unsigned short*)outp;
#pragma unroll
        for (int r = 0; r < 4; ++r)
          o[(size_t)(mg + r) * 1024 + ng] = f2b(acc[mt][nt][r] + bb_);
      } else {   // MODE 1: per-head-transposed V
        unsigned short* o = (unsigned short*)outp;
        int bb = mg >> 11, s0 = mg & 2047;
        int hh = ng >> 6, dd = ng & 63;
        ushort4 pk;
        pk.x = f2b(acc[mt][nt][0] + bb_);
        pk.y = f2b(acc[mt][nt][1] + bb_);
        pk.z = f2b(acc[mt][nt][2] + bb_);
        pk.w = f2b(acc[mt][nt][3] + bb_);
        *(ushort4*)&o[(((size_t)bb * Hc + hh) * 64 + dd) * Sc + s0] = pk;
      }
    }
  }
}

// -------------------------------------------- 128x128 GEMM core, BK=64 (r8)
// Round-8 structure verbatim. Used for out_gemm (512 blocks = 2/CU -> weak
// cross-block cover -> fewer drain events win).
template<int MODE>
__device__ __forceinline__ void gemm128_b64(
    const unsigned short* __restrict__ A, const unsigned short* __restrict__ W,
    const float* __restrict__ bias, void* __restrict__ outp,
    int m0, int n0, unsigned short* lA, unsigned short* lB)
{
  const int tid = threadIdx.x;
  const int w = tid >> 6, lane = tid & 63;
  const int g = lane >> 4, c = lane & 15;
  const int wr = w >> 1, wc = w & 1;

  f32x4 acc[4][4];
#pragma unroll
  for (int i = 0; i < 4; ++i)
#pragma unroll
    for (int j = 0; j < 4; ++j) acc[i][j] = f32x4{0.f, 0.f, 0.f, 0.f};

  const int lrow8 = lane >> 3;            // 0..7: row within 8-row stage stripe
  const int gslot = (lane & 7) ^ lrow8;   // pre-swizzled 16B chunk in 64-elem row

  const unsigned short* ap[4];
  const unsigned short* bp[4];
#pragma unroll
  for (int j = 0; j < 4; ++j) {
    int row = (j * 4 + w) * 8 + lrow8;
    ap[j] = A + (size_t)(m0 + row) * 1024 + gslot * 8;
    bp[j] = W + (size_t)(n0 + row) * 1024 + gslot * 8;
  }

  const int sl0 = (g ^ (c & 7)) << 4;
  const int sl1 = ((4 ^ g) ^ (c & 7)) << 4;
  const char* lA0 = (const char*)lA + (wr * 64 + c) * 128 + sl0;
  const char* lA1 = (const char*)lA + (wr * 64 + c) * 128 + sl1;
  const char* lB0 = (const char*)lB + (wc * 64 + c) * 128 + sl0;
  const char* lB1 = (const char*)lB + (wc * 64 + c) * 128 + sl1;

#define STAGE64                                             \
  do {                                                      \
    _Pragma("unroll")                                       \
    for (int j = 0; j < 4; ++j) {                           \
      glds16(ap[j], (char*)lA + (j * 4 + w) * 1024);        \
      glds16(bp[j], (char*)lB + (j * 4 + w) * 1024);        \
      ap[j] += 64; bp[j] += 64;                             \
    }                                                       \
  } while (0)

  STAGE64;
  for (int t = 0; t < 16; ++t) {
    asm volatile("s_waitcnt vmcnt(0)" ::: "memory");
    __builtin_amdgcn_s_barrier();
    asm volatile("" ::: "memory");

#pragma unroll
    for (int ks = 0; ks < 2; ++ks) {
      short8 aF[4], bF[4];
#pragma unroll
      for (int mt = 0; mt < 4; ++mt)
        aF[mt] = *(const short8*)((ks ? lA1 : lA0) + mt * 2048);
#pragma unroll
      for (int nt = 0; nt < 4; ++nt)
        bF[nt] = *(const short8*)((ks ? lB1 : lB0) + nt * 2048);
#pragma unroll
      for (int mt = 0; mt < 4; ++mt)
#pragma unroll
        for (int nt = 0; nt < 4; ++nt)
          acc[mt][nt] = __builtin_amdgcn_mfma_f32_16x16x32_bf16(
              aF[mt], bF[nt], acc[mt][nt], 0, 0, 0);
    }
    asm volatile("" ::: "memory");
    __builtin_amdgcn_s_barrier();
    asm volatile("" ::: "memory");
    if (t + 1 < 16) STAGE64;
  }
#undef STAGE64

#pragma unroll
  for (int mt = 0; mt < 4; ++mt) {
    int mg = m0 + wr * 64 + mt * 16 + 4 * g;
#pragma unroll
    for (int nt = 0; nt < 4; ++nt) {
      int ng = n0 + wc * 64 + nt * 16 + c;
      float bb_ = bias[ng];
      if constexpr (MODE == 2) {
        float* o = (float*)outp;
#pragma unroll
        for (int r = 0; r < 4; ++r)
          o[(size_t)(mg + r) * 1024 + ng] = acc[mt][nt][r] + bb_;
      } else {
        unsigned short* o = (unsigned short*)outp;
#pragma unroll
        for (int r = 0; r < 4; ++r)
          o[(size_t)(mg + r) * 1024 + ng] = f2b(acc[mt][nt][r] + bb_);
      }
    }
  }
}

// grid (64, 24): x-dim = m-tile so all 24 n/which-blocks of one m-tile land
// on the same XCD (linear id % 8 == x % 8) -> A-tile in one L2.
__global__ __launch_bounds__(256) void qkv_gemm(
    const float* __restrict__ x,
    const unsigned short* __restrict__ wqb, const unsigned short* __restrict__ wkb,
    const unsigned short* __restrict__ wvb,
    const float* __restrict__ bq, const float* __restrict__ bk,
    const float* __restrict__ bv,
    unsigned short* __restrict__ qo, unsigned short* __restrict__ ko,
    unsigned short* __restrict__ vto)
{
  __shared__ float lA[128 * 32];               // 16KB f32 A-tile
  __shared__ unsigned short lB[128 * 32];      // 8KB bf16 B-tile
  int m0 = blockIdx.x * 128;
  int which = blockIdx.y >> 3;
  int n0 = (blockIdx.y & 7) * 128;
  if (which == 0)      gemm128_xf32<0>(x, wqb, bq, qo, m0, n0, lA, lB);
  else if (which == 1) gemm128_xf32<0>(x, wkb, bk, ko, m0, n0, lA, lB);
  else                 gemm128_xf32<1>(x, wvb, bv, vto, m0, n0, lA, lB);
}

// grid (64, 8): x = m-tile (same-XCD A sharing); BK=64 core (2 blocks/CU)
__global__ __launch_bounds__(256) void out_gemm(
    const unsigned short* __restrict__ ao, const unsigned short* __restrict__ wob,
    const float* __restrict__ bo, float* __restrict__ out)
{
  __shared__ unsigned short lA[128 * 64], lB[128 * 64];
  gemm128_b64<2>(ao, wob, bo, out, blockIdx.x * 128, blockIdx.y * 128, lA, lB);
}

// ----------------------------------------------------------- flash attention
// r14/r12 staged version verbatim (known-good ~55us): LDS double-buffered
// K/V staging (coalesced glds16 -> swizzled ds_read), unpaired q-tiles
// (1024 blocks, 4/CU), T12 swapped-operand in-register softmax, T13
// defer-rescale, 4-chain reductions.
__global__ __launch_bounds__(256, 4) void attn_kernel(
    const unsigned short* __restrict__ qg, const unsigned short* __restrict__ kg,
    const unsigned short* __restrict__ vtg, unsigned short* __restrict__ ao)
{
  __shared__ unsigned short lK[2][64 * 64];
  __shared__ unsigned short lV[2][64 * 64];

  const int bh = blockIdx.x;
  const int qt = 15 - blockIdx.y;          // heavy first
  const int b = bh >> 4, h = bh & 15;
  const int tid = threadIdx.x, w = tid >> 6, lane = tid & 63;
  const int qr = lane & 31, hi = lane >> 5;
  const int qbase = qt * 128 + 32 * w;
  constexpr float CE = 0.125f * 1.44269504f;   // fold /sqrt(64) and log2(e)

  // Q as B-operand: col=q=qr, k(d) = 16i + 8hi + j
  short8 qB[4];
  {
    const unsigned short* qp = qg + (size_t)(b * Sc + qbase + qr) * Dc + h * 64 + 8 * hi;
#pragma unroll
    for (int i = 0; i < 4; ++i)
      qB[i] = *(const short8*)(qp + 16 * i);
  }

  float m_ = -3e38f, lv = 0.f;
  f32x16 oT[2];
#pragma unroll
  for (int n = 0; n < 2; ++n)
#pragma unroll
    for (int r = 0; r < 16; ++r) oT[n][r] = 0.f;

  const int srow8 = lane >> 3;
  const int sslot = lane & 7;
  const unsigned short* kb_ = kg + (size_t)b * Sc * Dc + h * 64;
  const unsigned short* vb_ = vtg + (size_t)bh * 64 * Sc;

  auto stage = [&](int buf, int t) {
    const int kv0 = t * 64;
#pragma unroll
    for (int i = 0; i < 2; ++i) {
      int row = i * 32 + w * 8 + srow8;
      int gch = sslot ^ (row & 7);
      glds16(kb_ + (size_t)(kv0 + row) * Dc + gch * 8,
             (char*)lK[buf] + i * 4096 + w * 1024);
      glds16(vb_ + (size_t)row * Sc + kv0 + gch * 8,
             (char*)lV[buf] + i * 4096 + w * 1024);
    }
  };

  const int ntl = 2 * (qt + 1);
  stage(0, 0);
  asm volatile("s_waitcnt vmcnt(0)" ::: "memory");
  __builtin_amdgcn_s_barrier();
  asm volatile("" ::: "memory");

  for (int t = 0; t < ntl; ++t) {
    const int cur = t & 1;
    const int kv0 = t * 64;
    if (t + 1 < ntl) stage(cur ^ 1, t + 1);

    if (kv0 <= qbase + 31) {   // wave-uniform causal skip
      // K as A-operand: row=k-idx, d-chunk 2i+hi
      short8 kA[2][4];
#pragma unroll
      for (int kblk = 0; kblk < 2; ++kblk) {
        const int row = kblk * 32 + qr;
        const int swz = (row & 7) << 4;
#pragma unroll
        for (int i = 0; i < 4; ++i)
          kA[kblk][i] = *(const short8*)((const char*)lK[cur] + row * 128 +
                          (((2 * i + hi) * 16) ^ swz));
      }

      // ---- S^T = K Q (32k x 32q per block, 2 k-blocks)
      f32x16 sT[2];
      __builtin_amdgcn_s_setprio(1);
#pragma unroll
      for (int kblk = 0; kblk < 2; ++kblk) {
        f32x16 s;
#pragma unroll
        for (int r = 0; r < 16; ++r) s[r] = 0.f;
#pragma unroll
        for (int i = 0; i < 4; ++i)
          s = __builtin_amdgcn_mfma_f32_32x32x16_bf16(kA[kblk][i], qB[i],
                                                      s, 0, 0, 0);
        sT[kblk] = s;
      }
      __builtin_amdgcn_s_setprio(0);

      // ---- causal mask (partial tiles only); q=qbase+qr, k from C-layout
      if (kv0 + 63 > qbase) {
        const int q = qbase + qr;
#pragma unroll
        for (int kblk = 0; kblk < 2; ++kblk)
#pragma unroll
          for (int r = 0; r < 16; ++r) {
            int k = kv0 + kblk * 32 + (r & 3) + 8 * (r >> 2) + 4 * hi;
            if (k > q) sT[kblk][r] = -1e30f;
          }
      }

      // ---- online softmax; 4-chain reductions (T17 max3-friendly)
      float mx;
      {
        float x0 = fmaxf(sT[0][0], sT[1][0]);
        float x1 = fmaxf(sT[0][1], sT[1][1]);
        float x2 = fmaxf(sT[0][2], sT[1][2]);
        float x3 = fmaxf(sT[0][3], sT[1][3]);
#pragma unroll
        for (int r = 4; r < 16; r += 4) {
          x0 = fmaxf(x0, fmaxf(sT[0][r + 0], sT[1][r + 0]));
          x1 = fmaxf(x1, fmaxf(sT[0][r + 1], sT[1][r + 1]));
          x2 = fmaxf(x2, fmaxf(sT[0][r + 2], sT[1][r + 2]));
          x3 = fmaxf(x3, fmaxf(sT[0][r + 3], sT[1][r + 3]));
        }
        mx = fmaxf(fmaxf(x0, x1), fmaxf(x2, x3));
        mx = fmaxf(mx, __shfl_xor(mx, 32));
      }

      if (!__all(mx <= m_ + 64.f)) {   // T13 defer-rescale (8 ln-units)
        const float mo = m_;
        const float mn = fmaxf(mo, mx);
        const float sf = __builtin_amdgcn_exp2f((mo - mn) * CE);
        m_ = mn;
        lv *= sf;
#pragma unroll
        for (int n = 0; n < 2; ++n)
#pragma unroll
          for (int r = 0; r < 16; ++r) oT[n][r] *= sf;
      }
      const float mc = m_ * CE;
      {
        float s0 = 0.f, s1 = 0.f, s2 = 0.f, s3 = 0.f;
#pragma unroll
        for (int kblk = 0; kblk < 2; ++kblk)
#pragma unroll
          for (int r = 0; r < 16; r += 4) {
            float p0 = __builtin_amdgcn_exp2f(sT[kblk][r + 0] * CE - mc);
            float p1 = __builtin_amdgcn_exp2f(sT[kblk][r + 1] * CE - mc);
            float p2 = __builtin_amdgcn_exp2f(sT[kblk][r + 2] * CE - mc);
            float p3 = __builtin_amdgcn_exp2f(sT[kblk][r + 3] * CE - mc);
            sT[kblk][r + 0] = p0; sT[kblk][r + 1] = p1;
            sT[kblk][r + 2] = p2; sT[kblk][r + 3] = p3;
            s0 += p0; s1 += p1; s2 += p2; s3 += p3;
          }
        lv += (s0 + s1) + (s2 + s3);   // per-lane partial; xor-32 at end
      }

      // ---- P^T -> bf16 B-frags, in-register exchange across xor-32
      short8 pB[4];
#pragma unroll
      for (int kblk = 0; kblk < 2; ++kblk) {
        uint32_t pk[4][2];
#pragma unroll
        for (int qp = 0; qp < 4; ++qp)
#pragma unroll
          for (int rp = 0; rp < 2; ++rp)
            pk[qp][rp] = cvtpk(sT[kblk][4 * qp + 2 * rp],
                               sT[kblk][4 * qp + 2 * rp + 1]);
#pragma unroll
        for (int m2 = 0; m2 < 2; ++m2) {
          uint32_t s0 = hi ? pk[2 * m2][0] : pk[2 * m2 + 1][0];
          uint32_t s1 = hi ? pk[2 * m2][1] : pk[2 * m2 + 1][1];
          uint32_t r0 = __shfl_xor(s0, 32);
          uint32_t r1 = __shfl_xor(s1, 32);
          uint32_t w0 = hi ? r0 : pk[2 * m2][0];
          uint32_t w1 = hi ? r1 : pk[2 * m2][1];
          uint32_t w2 = hi ? pk[2 * m2 + 1][0] : r0;
          uint32_t w3 = hi ? pk[2 * m2 + 1][1] : r1;
          uint32_t tmp[4] = { w0, w1, w2, w3 };
          pB[2 * kblk + m2] = *(const short8*)tmp;
        }
      }

      // V^T as A-operand: row=d, kv-chunk 2m+hi
      short8 vA[2][4];
#pragma unroll
      for (int n = 0; n < 2; ++n) {
        const int row = 32 * n + qr;
        const int swz = (row & 7) << 4;
#pragma unroll
        for (int m = 0; m < 4; ++m)
          vA[n][m] = *(const short8*)((const char*)lV[cur] + row * 128 +
                       (((2 * m + hi) * 16) ^ swz));
      }

      // ---- O^T += V^T P^T
      __builtin_amdgcn_s_setprio(1);
#pragma unroll
      for (int n = 0; n < 2; ++n)
#pragma unroll
        for (int m = 0; m < 4; ++m)
          oT[n] = __builtin_amdgcn_mfma_f32_32x32x16_bf16(
              vA[n][m], pB[m], oT[n], 0, 0, 0);
      __builtin_amdgcn_s_setprio(0);
    }

    asm volatile("s_waitcnt vmcnt(0)" ::: "memory");
    __builtin_amdgcn_s_barrier();
    asm volatile("" ::: "memory");
  }

  // ---- finalize: full row-sum via xor-32, normalize, packed store
  {
    float l = lv + __shfl_xor(lv, 32);
    float inv = 1.0f / l;
    const int qrow = qbase + qr;
    unsigned short* op = ao + (size_t)(b * Sc + qrow) * Dc + h * 64;
#pragma unroll
    for (int n = 0; n < 2; ++n)
#pragma unroll
      for (int rg = 0; rg < 4; ++rg) {
        ushort4 pkv;
        pkv.x = f2b(oT[n][4 * rg + 0] * inv);
        pkv.y = f2b(oT[n][4 * rg + 1] * inv);
        pkv.z = f2b(oT[n][4 * rg + 2] * inv);
        pkv.w = f2b(oT[n][4 * rg + 3] * inv);
        *(ushort4*)(op + 32 * n + 8 * rg + 4 * hi) = pkv;
      }
  }
}

// ------------------------------------------------------------------- launch
extern "C" void kernel_launch(void* const* d_in, const int* in_sizes, int n_in,
                              void* d_out, int out_size, void* d_ws, size_t ws_size,
                              hipStream_t stream) {
  const float* x  = (const float*)d_in[0];
  // d_in[1] = mask: causal triu(k=1), applied analytically in attn_kernel
  const float* wq = (const float*)d_in[2];
  const float* bq = (const float*)d_in[3];
  const float* wk = (const float*)d_in[4];
  const float* bk = (const float*)d_in[5];
  const float* wv = (const float*)d_in[6];
  const float* bv = (const float*)d_in[7];
  const float* wo = (const float*)d_in[8];
  const float* bo = (const float*)d_in[9];
  float* out = (float*)d_out;

  char* ws = (char*)d_ws;
  unsigned short* wqb = (unsigned short*)(ws + 16777216);
  unsigned short* wkb = (unsigned short*)(ws + 18874368);
  unsigned short* wvb = (unsigned short*)(ws + 20971520);
  unsigned short* wob = (unsigned short*)(ws + 23068672);
  unsigned short* qb  = (unsigned short*)(ws + 25165824);
  unsigned short* kb  = (unsigned short*)(ws + 41943040);
  unsigned short* vtb = (unsigned short*)(ws + 58720256);
  unsigned short* aob = (unsigned short*)(ws + 75497472);

  cast_w4<<<dim3(1024, 4), 256, 0, stream>>>(wq, wk, wv, wo, wqb, wkb, wvb, wob);

  qkv_gemm<<<dim3(64, 24), 256, 0, stream>>>(x, wqb, wkb, wvb, bq, bk, bv,
                                             qb, kb, vtb);
  attn_kernel<<<dim3(64, 16), 256, 0, stream>>>(qb, kb, vtb, aob);
  out_gemm<<<dim3(64, 8), 256, 0, stream>>>(aob, wob, bo, out);
}

// Round 16
// 162.702 us; speedup vs baseline: 1.0988x; 1.0988x over previous
//
#include <hip/hip_runtime.h>
#include <hip/hip_bf16.h>
#include <stdint.h>

typedef __attribute__((ext_vector_type(8))) short short8;
typedef __attribute__((ext_vector_type(4))) float f32x4;
typedef __attribute__((ext_vector_type(16))) float f32x16;

#define AS1 __attribute__((address_space(1)))
#define AS3 __attribute__((address_space(3)))

constexpr int Bc = 4, Sc = 2048, Dc = 1024, Hc = 16;

__device__ __forceinline__ unsigned short f2b(float x) {
  __hip_bfloat16 h = __float2bfloat16(x);
  return *reinterpret_cast<unsigned short*>(&h);
}

__device__ __forceinline__ uint32_t cvtpk(float lo, float hi) {
  uint32_t r;
  asm("v_cvt_pk_bf16_f32 %0, %1, %2" : "=v"(r) : "v"(lo), "v"(hi));
  return r;
}

// async global->LDS, 16B per lane; lds ptr must be wave-uniform (HW adds lane*16)
__device__ __forceinline__ void glds16(const void* g, void* l) {
  __builtin_amdgcn_global_load_lds((const AS1 uint32_t*)g, (AS3 uint32_t*)l, 16, 0, 0);
}

// ------------------------------------------------------- merged cast kernel
// One launch for x (2M float4) + 4 weights (256K float4 each). Per-block
// uniform source selection (ranges are block-aligned). No divergence.
// r15 lesson: do NOT fuse the x-cast into qkv (cvt_pk + f32 staging on the
// critical path cost 33us to save 9us). Standalone cast is HBM-floor-bound.
__global__ void cast_all(const float* __restrict__ x,
                         const float* __restrict__ wq, const float* __restrict__ wk,
                         const float* __restrict__ wv, const float* __restrict__ wo,
                         unsigned short* __restrict__ xb,
                         unsigned short* __restrict__ oq, unsigned short* __restrict__ ok,
                         unsigned short* __restrict__ ov, unsigned short* __restrict__ oo) {
  int blk = blockIdx.x;
  const float* in;
  unsigned short* out;
  int base;
  if (blk < 8192)      { in = x;  out = xb; base = 0; }
  else if (blk < 9216) { in = wq; out = oq; base = 8192; }
  else if (blk < 10240){ in = wk; out = ok; base = 9216; }
  else if (blk < 11264){ in = wv; out = ov; base = 10240; }
  else                 { in = wo; out = oo; base = 11264; }
  int i = (blk - base) * blockDim.x + threadIdx.x;
  float4 a = ((const float4*)in)[i];
  ushort4 o;
  o.x = f2b(a.x); o.y = f2b(a.y); o.z = f2b(a.z); o.w = f2b(a.w);
  ((ushort4*)out)[i] = o;
}

// -------------------------------------------- 128x128 GEMM core, BK=32 (r4)
// Round-4 proven structure verbatim (~76us on qkv, 678 TF = the 2-phase
// structural ceiling): single 16KB buffers, stage -> __syncthreads (drain)
// -> ds_read+MFMA -> __syncthreads. Conflicts on fragment reads accepted
// (regime gate m233/m252: stage+drain dominates; r4 76us w/ 6.3M conflicts
// vs r9 80us w/ 0). Every pipelining variant tried (r5-r9: dbuf, counted
// vmcnt, BK=64, swizzle) measured at or above this time.
template<int MODE>
__device__ __forceinline__ void gemm128_b32(
    const unsigned short* __restrict__ A, const unsigned short* __restrict__ W,
    const float* __restrict__ bias, void* __restrict__ outp,
    int m0, int n0, unsigned short* lA, unsigned short* lB)
{
  const int tid = threadIdx.x;
  const int w = tid >> 6, lane = tid & 63;
  const int g = lane >> 4, c = lane & 15;
  const int wr = w >> 1, wc = w & 1;

  f32x4 acc[4][4];
#pragma unroll
  for (int i = 0; i < 4; ++i)
#pragma unroll
    for (int j = 0; j < 4; ++j) acc[i][j] = f32x4{0.f, 0.f, 0.f, 0.f};

  const int srow = lane >> 2;          // 0..15
  const int schunk = (lane & 3) * 8;   // element offset of 16B chunk

  for (int k0 = 0; k0 < 1024; k0 += 32) {
#pragma unroll
    for (int i = 0; i < 2; ++i) {
      int row = i * 64 + w * 16 + srow;
      glds16(A + (size_t)(m0 + row) * 1024 + k0 + schunk,
             (char*)lA + i * 4096 + w * 1024);
      glds16(W + (size_t)(n0 + row) * 1024 + k0 + schunk,
             (char*)lB + i * 4096 + w * 1024);
    }
    __syncthreads();

    short8 aF[4], bF[4];
#pragma unroll
    for (int mt = 0; mt < 4; ++mt) {
      int row = wr * 64 + mt * 16 + c;
      aF[mt] = *(const short8*)&lA[row * 32 + g * 8];
    }
#pragma unroll
    for (int nt = 0; nt < 4; ++nt) {
      int row = wc * 64 + nt * 16 + c;
      bF[nt] = *(const short8*)&lB[row * 32 + g * 8];
    }
#pragma unroll
    for (int mt = 0; mt < 4; ++mt)
#pragma unroll
      for (int nt = 0; nt < 4; ++nt)
        acc[mt][nt] = __builtin_amdgcn_mfma_f32_16x16x32_bf16(aF[mt], bF[nt],
                                                              acc[mt][nt], 0, 0, 0);
    __syncthreads();
  }

  // epilogue: C row = 4g+reg, col = c (per 16x16 tile)
#pragma unroll
  for (int mt = 0; mt < 4; ++mt) {
    int mg = m0 + wr * 64 + mt * 16 + 4 * g;
#pragma unroll
    for (int nt = 0; nt < 4; ++nt) {
      int ng = n0 + wc * 64 + nt * 16 + c;
      float bb_ = bias[ng];
      if constexpr (MODE == 0) {
        unsigned short* o = (unsigned short*)outp;
#pragma unroll
        for (int r = 0; r < 4; ++r)
          o[(size_t)(mg + r) * 1024 + ng] = f2b(acc[mt][nt][r] + bb_);
      } else if constexpr (MODE == 1) {
        unsigned short* o = (unsigned short*)outp;
        int bb = mg >> 11, s0 = mg & 2047;   // batch, seq
        int hh = ng >> 6, dd = ng & 63;      // head, depth
        ushort4 pk;
        pk.x = f2b(acc[mt][nt][0] + bb_);
        pk.y = f2b(acc[mt][nt][1] + bb_);
        pk.z = f2b(acc[mt][nt][2] + bb_);
        pk.w = f2b(acc[mt][nt][3] + bb_);
        *(ushort4*)&o[(((size_t)bb * Hc + hh) * 64 + dd) * Sc + s0] = pk;
      } else {
        float* o = (float*)outp;
#pragma unroll
        for (int r = 0; r < 4; ++r)
          o[(size_t)(mg + r) * 1024 + ng] = acc[mt][nt][r] + bb_;
      }
    }
  }
}

// -------------------------------------------- 128x128 GEMM core, BK=64 (r8)
// Round-8 structure verbatim. Used for out_gemm (512 blocks = 2/CU -> weak
// cross-block cover -> fewer drain events win).
template<int MODE>
__device__ __forceinline__ void gemm128_b64(
    const unsigned short* __restrict__ A, const unsigned short* __restrict__ W,
    const float* __restrict__ bias, void* __restrict__ outp,
    int m0, int n0, unsigned short* lA, unsigned short* lB)
{
  const int tid = threadIdx.x;
  const int w = tid >> 6, lane = tid & 63;
  const int g = lane >> 4, c = lane & 15;
  const int wr = w >> 1, wc = w & 1;

  f32x4 acc[4][4];
#pragma unroll
  for (int i = 0; i < 4; ++i)
#pragma unroll
    for (int j = 0; j < 4; ++j) acc[i][j] = f32x4{0.f, 0.f, 0.f, 0.f};

  const int lrow8 = lane >> 3;            // 0..7: row within 8-row stage stripe
  const int gslot = (lane & 7) ^ lrow8;   // pre-swizzled 16B chunk in 64-elem row

  const unsigned short* ap[4];
  const unsigned short* bp[4];
#pragma unroll
  for (int j = 0; j < 4; ++j) {
    int row = (j * 4 + w) * 8 + lrow8;
    ap[j] = A + (size_t)(m0 + row) * 1024 + gslot * 8;
    bp[j] = W + (size_t)(n0 + row) * 1024 + gslot * 8;
  }

  const int sl0 = (g ^ (c & 7)) << 4;
  const int sl1 = ((4 ^ g) ^ (c & 7)) << 4;
  const char* lA0 = (const char*)lA + (wr * 64 + c) * 128 + sl0;
  const char* lA1 = (const char*)lA + (wr * 64 + c) * 128 + sl1;
  const char* lB0 = (const char*)lB + (wc * 64 + c) * 128 + sl0;
  const char* lB1 = (const char*)lB + (wc * 64 + c) * 128 + sl1;

#define STAGE64                                             \
  do {                                                      \
    _Pragma("unroll")                                       \
    for (int j = 0; j < 4; ++j) {                           \
      glds16(ap[j], (char*)lA + (j * 4 + w) * 1024);        \
      glds16(bp[j], (char*)lB + (j * 4 + w) * 1024);        \
      ap[j] += 64; bp[j] += 64;                             \
    }                                                       \
  } while (0)

  STAGE64;
  for (int t = 0; t < 16; ++t) {
    asm volatile("s_waitcnt vmcnt(0)" ::: "memory");
    __builtin_amdgcn_s_barrier();
    asm volatile("" ::: "memory");

#pragma unroll
    for (int ks = 0; ks < 2; ++ks) {
      short8 aF[4], bF[4];
#pragma unroll
      for (int mt = 0; mt < 4; ++mt)
        aF[mt] = *(const short8*)((ks ? lA1 : lA0) + mt * 2048);
#pragma unroll
      for (int nt = 0; nt < 4; ++nt)
        bF[nt] = *(const short8*)((ks ? lB1 : lB0) + nt * 2048);
#pragma unroll
      for (int mt = 0; mt < 4; ++mt)
#pragma unroll
        for (int nt = 0; nt < 4; ++nt)
          acc[mt][nt] = __builtin_amdgcn_mfma_f32_16x16x32_bf16(
              aF[mt], bF[nt], acc[mt][nt], 0, 0, 0);
    }
    asm volatile("" ::: "memory");
    __builtin_amdgcn_s_barrier();
    asm volatile("" ::: "memory");
    if (t + 1 < 16) STAGE64;
  }
#undef STAGE64

#pragma unroll
  for (int mt = 0; mt < 4; ++mt) {
    int mg = m0 + wr * 64 + mt * 16 + 4 * g;
#pragma unroll
    for (int nt = 0; nt < 4; ++nt) {
      int ng = n0 + wc * 64 + nt * 16 + c;
      float bb_ = bias[ng];
      if constexpr (MODE == 2) {
        float* o = (float*)outp;
#pragma unroll
        for (int r = 0; r < 4; ++r)
          o[(size_t)(mg + r) * 1024 + ng] = acc[mt][nt][r] + bb_;
      } else {
        unsigned short* o = (unsigned short*)outp;
#pragma unroll
        for (int r = 0; r < 4; ++r)
          o[(size_t)(mg + r) * 1024 + ng] = f2b(acc[mt][nt][r] + bb_);
      }
    }
  }
}

// grid (64, 24): x = m-tile so all 24 n/which-blocks of one m-tile land on the
// same XCD (linear id % 8 == x % 8) -> A-tile fetched into one L2, not eight.
__global__ __launch_bounds__(256) void qkv_gemm(
    const unsigned short* __restrict__ xb,
    const unsigned short* __restrict__ wqb, const unsigned short* __restrict__ wkb,
    const unsigned short* __restrict__ wvb,
    const float* __restrict__ bq, const float* __restrict__ bk,
    const float* __restrict__ bv,
    unsigned short* __restrict__ qo, unsigned short* __restrict__ ko,
    unsigned short* __restrict__ vto)
{
  __shared__ unsigned short lA[128 * 32], lB[128 * 32];
  int m0 = blockIdx.x * 128;
  int which = blockIdx.y >> 3;
  int n0 = (blockIdx.y & 7) * 128;
  if (which == 0)      gemm128_b32<0>(xb, wqb, bq, qo, m0, n0, lA, lB);
  else if (which == 1) gemm128_b32<0>(xb, wkb, bk, ko, m0, n0, lA, lB);
  else                 gemm128_b32<1>(xb, wvb, bv, vto, m0, n0, lA, lB);
}

// grid (64, 8): x = m-tile (same-XCD A sharing); BK=64 core (2 blocks/CU)
__global__ __launch_bounds__(256) void out_gemm(
    const unsigned short* __restrict__ ao, const unsigned short* __restrict__ wob,
    const float* __restrict__ bo, float* __restrict__ out)
{
  __shared__ unsigned short lA[128 * 64], lB[128 * 64];
  gemm128_b64<2>(ao, wob, bo, out, blockIdx.x * 128, blockIdx.y * 128, lA, lB);
}

// ----------------------------------------------------------- flash attention
// r12/r14 staged version verbatim (known-good ~55us): LDS double-buffered
// K/V staging (coalesced glds16 -> swizzled ds_read; staging IS the
// coalescing transform, r13 lesson), unpaired q-tiles (1024 blocks, 4/CU),
// T12 swapped-operand in-register softmax, T13 defer-rescale, 4-chain
// reductions.
__global__ __launch_bounds__(256, 4) void attn_kernel(
    const unsigned short* __restrict__ qg, const unsigned short* __restrict__ kg,
    const unsigned short* __restrict__ vtg, unsigned short* __restrict__ ao)
{
  __shared__ unsigned short lK[2][64 * 64];
  __shared__ unsigned short lV[2][64 * 64];

  const int bh = blockIdx.x;
  const int qt = 15 - blockIdx.y;          // heavy first
  const int b = bh >> 4, h = bh & 15;
  const int tid = threadIdx.x, w = tid >> 6, lane = tid & 63;
  const int qr = lane & 31, hi = lane >> 5;
  const int qbase = qt * 128 + 32 * w;
  constexpr float CE = 0.125f * 1.44269504f;   // fold /sqrt(64) and log2(e)

  // Q as B-operand: col=q=qr, k(d) = 16i + 8hi + j
  short8 qB[4];
  {
    const unsigned short* qp = qg + (size_t)(b * Sc + qbase + qr) * Dc + h * 64 + 8 * hi;
#pragma unroll
    for (int i = 0; i < 4; ++i)
      qB[i] = *(const short8*)(qp + 16 * i);
  }

  float m_ = -3e38f, lv = 0.f;
  f32x16 oT[2];
#pragma unroll
  for (int n = 0; n < 2; ++n)
#pragma unroll
    for (int r = 0; r < 16; ++r) oT[n][r] = 0.f;

  const int srow8 = lane >> 3;
  const int sslot = lane & 7;
  const unsigned short* kb_ = kg + (size_t)b * Sc * Dc + h * 64;
  const unsigned short* vb_ = vtg + (size_t)bh * 64 * Sc;

  auto stage = [&](int buf, int t) {
    const int kv0 = t * 64;
#pragma unroll
    for (int i = 0; i < 2; ++i) {
      int row = i * 32 + w * 8 + srow8;
      int gch = sslot ^ (row & 7);
      glds16(kb_ + (size_t)(kv0 + row) * Dc + gch * 8,
             (char*)lK[buf] + i * 4096 + w * 1024);
      glds16(vb_ + (size_t)row * Sc + kv0 + gch * 8,
             (char*)lV[buf] + i * 4096 + w * 1024);
    }
  };

  const int ntl = 2 * (qt + 1);
  stage(0, 0);
  asm volatile("s_waitcnt vmcnt(0)" ::: "memory");
  __builtin_amdgcn_s_barrier();
  asm volatile("" ::: "memory");

  for (int t = 0; t < ntl; ++t) {
    const int cur = t & 1;
    const int kv0 = t * 64;
    if (t + 1 < ntl) stage(cur ^ 1, t + 1);

    if (kv0 <= qbase + 31) {   // wave-uniform causal skip
      // K as A-operand: row=k-idx, d-chunk 2i+hi
      short8 kA[2][4];
#pragma unroll
      for (int kblk = 0; kblk < 2; ++kblk) {
        const int row = kblk * 32 + qr;
        const int swz = (row & 7) << 4;
#pragma unroll
        for (int i = 0; i < 4; ++i)
          kA[kblk][i] = *(const short8*)((const char*)lK[cur] + row * 128 +
                          (((2 * i + hi) * 16) ^ swz));
      }

      // ---- S^T = K Q (32k x 32q per block, 2 k-blocks)
      f32x16 sT[2];
      __builtin_amdgcn_s_setprio(1);
#pragma unroll
      for (int kblk = 0; kblk < 2; ++kblk) {
        f32x16 s;
#pragma unroll
        for (int r = 0; r < 16; ++r) s[r] = 0.f;
#pragma unroll
        for (int i = 0; i < 4; ++i)
          s = __builtin_amdgcn_mfma_f32_32x32x16_bf16(kA[kblk][i], qB[i],
                                                      s, 0, 0, 0);
        sT[kblk] = s;
      }
      __builtin_amdgcn_s_setprio(0);

      // ---- causal mask (partial tiles only); q=qbase+qr, k from C-layout
      if (kv0 + 63 > qbase) {
        const int q = qbase + qr;
#pragma unroll
        for (int kblk = 0; kblk < 2; ++kblk)
#pragma unroll
          for (int r = 0; r < 16; ++r) {
            int k = kv0 + kblk * 32 + (r & 3) + 8 * (r >> 2) + 4 * hi;
            if (k > q) sT[kblk][r] = -1e30f;
          }
      }

      // ---- online softmax; 4-chain reductions (T17 max3-friendly)
      float mx;
      {
        float x0 = fmaxf(sT[0][0], sT[1][0]);
        float x1 = fmaxf(sT[0][1], sT[1][1]);
        float x2 = fmaxf(sT[0][2], sT[1][2]);
        float x3 = fmaxf(sT[0][3], sT[1][3]);
#pragma unroll
        for (int r = 4; r < 16; r += 4) {
          x0 = fmaxf(x0, fmaxf(sT[0][r + 0], sT[1][r + 0]));
          x1 = fmaxf(x1, fmaxf(sT[0][r + 1], sT[1][r + 1]));
          x2 = fmaxf(x2, fmaxf(sT[0][r + 2], sT[1][r + 2]));
          x3 = fmaxf(x3, fmaxf(sT[0][r + 3], sT[1][r + 3]));
        }
        mx = fmaxf(fmaxf(x0, x1), fmaxf(x2, x3));
        mx = fmaxf(mx, __shfl_xor(mx, 32));
      }

      if (!__all(mx <= m_ + 64.f)) {   // T13 defer-rescale (8 ln-units)
        const float mo = m_;
        const float mn = fmaxf(mo, mx);
        const float sf = __builtin_amdgcn_exp2f((mo - mn) * CE);
        m_ = mn;
        lv *= sf;
#pragma unroll
        for (int n = 0; n < 2; ++n)
#pragma unroll
          for (int r = 0; r < 16; ++r) oT[n][r] *= sf;
      }
      const float mc = m_ * CE;
      {
        float s0 = 0.f, s1 = 0.f, s2 = 0.f, s3 = 0.f;
#pragma unroll
        for (int kblk = 0; kblk < 2; ++kblk)
#pragma unroll
          for (int r = 0; r < 16; r += 4) {
            float p0 = __builtin_amdgcn_exp2f(sT[kblk][r + 0] * CE - mc);
            float p1 = __builtin_amdgcn_exp2f(sT[kblk][r + 1] * CE - mc);
            float p2 = __builtin_amdgcn_exp2f(sT[kblk][r + 2] * CE - mc);
            float p3 = __builtin_amdgcn_exp2f(sT[kblk][r + 3] * CE - mc);
            sT[kblk][r + 0] = p0; sT[kblk][r + 1] = p1;
            sT[kblk][r + 2] = p2; sT[kblk][r + 3] = p3;
            s0 += p0; s1 += p1; s2 += p2; s3 += p3;
          }
        lv += (s0 + s1) + (s2 + s3);   // per-lane partial; xor-32 at end
      }

      // ---- P^T -> bf16 B-frags, in-register exchange across xor-32
      short8 pB[4];
#pragma unroll
      for (int kblk = 0; kblk < 2; ++kblk) {
        uint32_t pk[4][2];
#pragma unroll
        for (int qp = 0; qp < 4; ++qp)
#pragma unroll
          for (int rp = 0; rp < 2; ++rp)
            pk[qp][rp] = cvtpk(sT[kblk][4 * qp + 2 * rp],
                               sT[kblk][4 * qp + 2 * rp + 1]);
#pragma unroll
        for (int m2 = 0; m2 < 2; ++m2) {
          uint32_t s0 = hi ? pk[2 * m2][0] : pk[2 * m2 + 1][0];
          uint32_t s1 = hi ? pk[2 * m2][1] : pk[2 * m2 + 1][1];
          uint32_t r0 = __shfl_xor(s0, 32);
          uint32_t r1 = __shfl_xor(s1, 32);
          uint32_t w0 = hi ? r0 : pk[2 * m2][0];
          uint32_t w1 = hi ? r1 : pk[2 * m2][1];
          uint32_t w2 = hi ? pk[2 * m2 + 1][0] : r0;
          uint32_t w3 = hi ? pk[2 * m2 + 1][1] : r1;
          uint32_t tmp[4] = { w0, w1, w2, w3 };
          pB[2 * kblk + m2] = *(const short8*)tmp;
        }
      }

      // V^T as A-operand: row=d, kv-chunk 2m+hi
      short8 vA[2][4];
#pragma unroll
      for (int n = 0; n < 2; ++n) {
        const int row = 32 * n + qr;
        const int swz = (row & 7) << 4;
#pragma unroll
        for (int m = 0; m < 4; ++m)
          vA[n][m] = *(const short8*)((const char*)lV[cur] + row * 128 +
                       (((2 * m + hi) * 16) ^ swz));
      }

      // ---- O^T += V^T P^T
      __builtin_amdgcn_s_setprio(1);
#pragma unroll
      for (int n = 0; n < 2; ++n)
#pragma unroll
        for (int m = 0; m < 4; ++m)
          oT[n] = __builtin_amdgcn_mfma_f32_32x32x16_bf16(
              vA[n][m], pB[m], oT[n], 0, 0, 0);
      __builtin_amdgcn_s_setprio(0);
    }

    asm volatile("s_waitcnt vmcnt(0)" ::: "memory");
    __builtin_amdgcn_s_barrier();
    asm volatile("" ::: "memory");
  }

  // ---- finalize: full row-sum via xor-32, normalize, packed store
  {
    float l = lv + __shfl_xor(lv, 32);
    float inv = 1.0f / l;
    const int qrow = qbase + qr;
    unsigned short* op = ao + (size_t)(b * Sc + qrow) * Dc + h * 64;
#pragma unroll
    for (int n = 0; n < 2; ++n)
#pragma unroll
      for (int rg = 0; rg < 4; ++rg) {
        ushort4 pkv;
        pkv.x = f2b(oT[n][4 * rg + 0] * inv);
        pkv.y = f2b(oT[n][4 * rg + 1] * inv);
        pkv.z = f2b(oT[n][4 * rg + 2] * inv);
        pkv.w = f2b(oT[n][4 * rg + 3] * inv);
        *(ushort4*)(op + 32 * n + 8 * rg + 4 * hi) = pkv;
      }
  }
}

// ------------------------------------------------------------------- launch
extern "C" void kernel_launch(void* const* d_in, const int* in_sizes, int n_in,
                              void* d_out, int out_size, void* d_ws, size_t ws_size,
                              hipStream_t stream) {
  const float* x  = (const float*)d_in[0];
  // d_in[1] = mask: causal triu(k=1), applied analytically in attn_kernel
  const float* wq = (const float*)d_in[2];
  const float* bq = (const float*)d_in[3];
  const float* wk = (const float*)d_in[4];
  const float* bk = (const float*)d_in[5];
  const float* wv = (const float*)d_in[6];
  const float* bv = (const float*)d_in[7];
  const float* wo = (const float*)d_in[8];
  const float* bo = (const float*)d_in[9];
  float* out = (float*)d_out;

  char* ws = (char*)d_ws;
  unsigned short* xb  = (unsigned short*)(ws);
  unsigned short* wqb = (unsigned short*)(ws + 16777216);
  unsigned short* wkb = (unsigned short*)(ws + 18874368);
  unsigned short* wvb = (unsigned short*)(ws + 20971520);
  unsigned short* wob = (unsigned short*)(ws + 23068672);
  unsigned short* qb  = (unsigned short*)(ws + 25165824);
  unsigned short* kb  = (unsigned short*)(ws + 41943040);
  unsigned short* vtb = (unsigned short*)(ws + 58720256);
  unsigned short* aob = (unsigned short*)(ws + 75497472);

  cast_all<<<12288, 256, 0, stream>>>(x, wq, wk, wv, wo, xb, wqb, wkb, wvb, wob);

  qkv_gemm<<<dim3(64, 24), 256, 0, stream>>>(xb, wqb, wkb, wvb, bq, bk, bv,
                                             qb, kb, vtb);
  attn_kernel<<<dim3(64, 16), 256, 0, stream>>>(qb, kb, vtb, aob);
  out_gemm<<<dim3(64, 8), 256, 0, stream>>>(aob, wob, bo, out);
}